// Round 2
// baseline (382.593 us; speedup 1.0000x reference)
//
#include <hip/hip_runtime.h>
#include <stdint.h>

typedef unsigned short ushort_t;
typedef __bf16 bf16x8 __attribute__((ext_vector_type(8)));
typedef float f32x4 __attribute__((ext_vector_type(4)));

#define TT   65536   // tokens (8*8192)
#define DD   256
#define FF   1024
#define EE   8
#define CAP  10240   // ceil(1.25*T/E) == 80*128 exactly

typedef __attribute__((address_space(1))) void gvoid;
typedef __attribute__((address_space(3))) void lvoid;

__device__ inline unsigned short f2bf(float f) {
  unsigned int u = __builtin_bit_cast(unsigned int, f);
  u += 0x7fffu + ((u >> 16) & 1u);   // round-to-nearest-even
  return (unsigned short)(u >> 16);
}
__device__ inline float bf2f(unsigned int u) {
  return __builtin_bit_cast(float, u << 16);
}
__device__ inline void gll16(const void* g, void* l) {
  __builtin_amdgcn_global_load_lds((gvoid*)(uintptr_t)g, (lvoid*)(uintptr_t)l, 16, 0, 0);
}

// ---------------- cast X (f32) -> xbf (bf16), 8 elems/thread ----------
__global__ __launch_bounds__(256) void cast_kernel(const float* __restrict__ X,
                                                   ushort_t* __restrict__ xbf)
{
  size_t i = ((size_t)blockIdx.x * 256 + threadIdx.x) * 8;
  float4 a = *(const float4*)(X + i);
  float4 b = *(const float4*)(X + i + 4);
  uint4 o;
  o.x = (unsigned)f2bf(a.x) | ((unsigned)f2bf(a.y) << 16);
  o.y = (unsigned)f2bf(a.z) | ((unsigned)f2bf(a.w) << 16);
  o.z = (unsigned)f2bf(b.x) | ((unsigned)f2bf(b.y) << 16);
  o.w = (unsigned)f2bf(b.z) | ((unsigned)f2bf(b.w) << 16);
  *(uint4*)(xbf + i) = o;
}

// ---------------- gating: 1 wave per token, fp64 logits ----------------
__global__ __launch_bounds__(256) void gate_kernel(
    const float* __restrict__ X, const float* __restrict__ GW,
    const float* __restrict__ GB, int* __restrict__ eidx,
    float* __restrict__ prob)
{
  const int w = threadIdx.x >> 6, lane = threadIdx.x & 63;
  const int tok = blockIdx.x * 4 + w;
  const float4 xv = *(const float4*)(X + (size_t)tok * DD + lane * 4);
  float xs[4] = {xv.x, xv.y, xv.z, xv.w};
  double acc[EE];
  #pragma unroll
  for (int e = 0; e < EE; e++) acc[e] = 0.0;
  #pragma unroll
  for (int dd = 0; dd < 4; dd++) {
    double xf = (double)xs[dd];
    const float4 g0 = *(const float4*)(GW + (size_t)(lane * 4 + dd) * EE);
    const float4 g1 = *(const float4*)(GW + (size_t)(lane * 4 + dd) * EE + 4);
    acc[0] += xf * (double)g0.x; acc[1] += xf * (double)g0.y;
    acc[2] += xf * (double)g0.z; acc[3] += xf * (double)g0.w;
    acc[4] += xf * (double)g1.x; acc[5] += xf * (double)g1.y;
    acc[6] += xf * (double)g1.z; acc[7] += xf * (double)g1.w;
  }
  #pragma unroll
  for (int off = 32; off >= 1; off >>= 1)
    #pragma unroll
    for (int e = 0; e < EE; e++)
      acc[e] += __shfl_xor(acc[e], off, 64);
  #pragma unroll
  for (int e = 0; e < EE; e++) acc[e] += (double)GB[e];
  int best = 0; double bm = acc[0];
  #pragma unroll
  for (int e = 1; e < EE; e++) if (acc[e] > bm) { bm = acc[e]; best = e; }
  float s = 0.f;
  #pragma unroll
  for (int e = 0; e < EE; e++) s += __expf((float)(acc[e] - bm));
  if (lane == 0) { eidx[tok] = best; prob[tok] = 1.0f / s; }
}

// ---------------- per-256-token-block expert histogram ----------------
__global__ __launch_bounds__(256) void hist_kernel(const int* __restrict__ eidx,
                                                   int* __restrict__ bh)
{
  __shared__ int h[EE];
  if (threadIdx.x < EE) h[threadIdx.x] = 0;
  __syncthreads();
  atomicAdd(&h[eidx[blockIdx.x * 256 + threadIdx.x]], 1);
  __syncthreads();
  if (threadIdx.x < EE) bh[blockIdx.x * EE + threadIdx.x] = h[threadIdx.x];
}

// ---------------- exclusive scan of block histograms (1 block) --------
__global__ __launch_bounds__(256) void scan_kernel(const int* __restrict__ bh,
                                                   int* __restrict__ bb,
                                                   int* __restrict__ counts)
{
  __shared__ int sh[256];
  const int tid = threadIdx.x;
  for (int e = 0; e < EE; e++) {
    int v = bh[tid * EE + e];
    int sum = v;
    sh[tid] = v;
    __syncthreads();
    for (int off = 1; off < 256; off <<= 1) {
      int add = (tid >= off) ? sh[tid - off] : 0;
      __syncthreads();
      sum += add;
      sh[tid] = sum;
      __syncthreads();
    }
    bb[tid * EE + e] = sum - v;          // exclusive base for this block
    if (tid == 255) counts[e] = sum;     // total per expert
    __syncthreads();
  }
}

// ---------------- token-order rank within expert; fill slot map -------
__global__ __launch_bounds__(256) void rank_kernel(const int* __restrict__ eidx,
                                                   const int* __restrict__ bb,
                                                   int* __restrict__ tfs,
                                                   int* __restrict__ tpos)
{
  __shared__ int wh[4][EE];
  const int tid = threadIdx.x, w = tid >> 6, lane = tid & 63;
  const int t = blockIdx.x * 256 + tid;
  const int e = eidx[t];
  const unsigned long long ltmask = (1ull << lane) - 1ull;
  int myrank = 0;
  #pragma unroll
  for (int ee = 0; ee < EE; ee++) {
    unsigned long long m = __ballot(e == ee);
    if (e == ee) myrank = __popcll(m & ltmask);
    if (lane == 0) wh[w][ee] = __popcll(m);
  }
  __syncthreads();
  int base = bb[blockIdx.x * EE + e];
  for (int ww = 0; ww < w; ww++) base += wh[ww][e];
  const int pos = base + myrank;
  tpos[t] = pos;
  if (pos < CAP) tfs[e * CAP + pos] = t;
}

// ---------------- zero dropped tokens' output rows (rare path) --------
__global__ __launch_bounds__(256) void zero_dropped_kernel(const int* __restrict__ tpos,
                                                           float* __restrict__ Y)
{
  const int t = blockIdx.x * 256 + threadIdx.x;
  if (tpos[t] >= CAP) {
    float4 z = {0.f, 0.f, 0.f, 0.f};
    float4* yp = (float4*)(Y + (size_t)t * DD);
    for (int i = 0; i < DD / 4; i++) yp[i] = z;
  }
}

// ------- 64x64 tiled transpose + f32->bf16 cast, per expert -----------
// src f32 [E][R][Cc] -> dst bf16 [E][Cc][R]
__global__ __launch_bounds__(256) void transpose_cast_kernel(const float* __restrict__ src,
                                                             ushort_t* __restrict__ dst,
                                                             int R, int Cc)
{
  __shared__ __align__(16) ushort_t tile[64][72];
  const size_t ebase = (size_t)blockIdx.z * R * Cc;
  const int r0 = blockIdx.y * 64, c0 = blockIdx.x * 64;
  #pragma unroll
  for (int it = 0; it < 4; it++) {
    int idx = threadIdx.x + it * 256;          // 1024 float4-loads
    int r = idx >> 4, c4 = (idx & 15) * 4;
    float4 v = *(const float4*)(src + ebase + (size_t)(r0 + r) * Cc + c0 + c4);
    ushort_t u[4] = {f2bf(v.x), f2bf(v.y), f2bf(v.z), f2bf(v.w)};
    *(uint2*)&tile[r][c4] = *(uint2*)u;
  }
  __syncthreads();
  #pragma unroll
  for (int it = 0; it < 2; it++) {
    int idx = threadIdx.x + it * 256;          // 512 8-elem stores
    int c = idx >> 3, r8 = (idx & 7) * 8;
    uint4 o;
    ushort_t* op = (ushort_t*)&o;
    #pragma unroll
    for (int j = 0; j < 8; j++) op[j] = tile[r8 + j][c];
    *(uint4*)(dst + ebase + (size_t)(c0 + c) * R + r0 + r8) = o;
  }
}

// ---------------- 128x128 MFMA GEMM, BK=64, global_load_lds staging ---
// G2=false: hmid[m,n] = relu(gather(xbf)[m,:] @ w1t[n,:] + b1)   (bf16 out)
// G2=true : Y[t,n]    = (hmid[m,:] @ w2t[n,:] + b2) * prob[t]    (f32 scatter)
template<int KD, int ND, bool G2>
__global__ __launch_bounds__(256) void gemm_kernel(
    const ushort_t* __restrict__ Asrc, const ushort_t* __restrict__ Bsrc,
    const float* __restrict__ bias, const int* __restrict__ tfs,
    const int* __restrict__ counts, const float* __restrict__ prob,
    const ushort_t* __restrict__ zrow, ushort_t* __restrict__ outb,
    float* __restrict__ outf, int base_e)
{
  __shared__ __align__(16) ushort_t At[128 * 64];
  __shared__ __align__(16) ushort_t Bt[128 * 64];
  const int ty = blockIdx.y;
  const int e = base_e + ty / 80;
  const int row0 = (ty % 80) * 128;
  const int cnt = counts[e];
  if (row0 >= cnt) return;                 // whole tile empty -> never read downstream
  const int n0 = blockIdx.x * 128;
  const int tid = threadIdx.x, lane = tid & 63, w = tid >> 6;
  const int sub = lane >> 3;                       // row-in-8 of this lane
  const int chunk = ((lane & 7) ^ sub) * 8;        // XOR-swizzled 16B chunk (elems)

  const ushort_t* ab[4];
  const ushort_t* bpt[4];
  const ushort_t* Bexp = Bsrc + (size_t)e * ND * KD;
  #pragma unroll
  for (int i = 0; i < 4; i++) {
    int r = w * 32 + i * 8 + sub;
    if (G2) {
      ab[i] = Asrc + (size_t)(ty * 128 + r) * KD + chunk;
    } else {
      int t = tfs[e * CAP + row0 + r];
      ab[i] = (t >= 0 ? Asrc + (size_t)t * KD : zrow) + chunk;
    }
    bpt[i] = Bexp + (size_t)(n0 + w * 32 + i * 8 + sub) * KD + chunk;
  }

  const f32x4 fzero = {0.f, 0.f, 0.f, 0.f};
  f32x4 acc[4][4];
  #pragma unroll
  for (int i = 0; i < 4; i++)
    #pragma unroll
    for (int j = 0; j < 4; j++) acc[i][j] = fzero;

  const int wm = (w >> 1) * 64, wn = (w & 1) * 64;

  for (int k0 = 0; k0 < KD; k0 += 64) {
    #pragma unroll
    for (int i = 0; i < 4; i++)
      gll16(ab[i] + k0, &At[(w * 32 + i * 8) * 64]);
    #pragma unroll
    for (int i = 0; i < 4; i++)
      gll16(bpt[i] + k0, &Bt[(w * 32 + i * 8) * 64]);
    __syncthreads();
    #pragma unroll
    for (int kk = 0; kk < 2; kk++) {
      const int cidx = kk * 4 + (lane >> 4);
      bf16x8 af[4], bg[4];
      #pragma unroll
      for (int i = 0; i < 4; i++) {
        int row = wm + i * 16 + (lane & 15);
        af[i] = *(const bf16x8*)&At[row * 64 + ((cidx ^ (row & 7)) * 8)];
      }
      #pragma unroll
      for (int j = 0; j < 4; j++) {
        int row = wn + j * 16 + (lane & 15);
        bg[j] = *(const bf16x8*)&Bt[row * 64 + ((cidx ^ (row & 7)) * 8)];
      }
      #pragma unroll
      for (int i = 0; i < 4; i++)
        #pragma unroll
        for (int j = 0; j < 4; j++)
          acc[i][j] = __builtin_amdgcn_mfma_f32_16x16x32_bf16(af[i], bg[j], acc[i][j], 0, 0, 0);
    }
    __syncthreads();
  }

  // epilogue (C/D layout: col=lane&15, row=(lane>>4)*4+reg — m89/m91 verified)
  float bn[4];
  #pragma unroll
  for (int j = 0; j < 4; j++)
    bn[j] = bias[e * ND + n0 + wn + j * 16 + (lane & 15)];
  if (!G2) {
    #pragma unroll
    for (int i = 0; i < 4; i++)
      #pragma unroll
      for (int r = 0; r < 4; r++) {
        int m = wm + i * 16 + (lane >> 4) * 4 + r;
        size_t ro = (size_t)(ty * 128 + m) * ND + n0;
        #pragma unroll
        for (int j = 0; j < 4; j++) {
          float v = acc[i][j][r] + bn[j];
          outb[ro + wn + j * 16 + (lane & 15)] = f2bf(v > 0.f ? v : 0.f);
        }
      }
  } else {
    #pragma unroll
    for (int i = 0; i < 4; i++)
      #pragma unroll
      for (int r = 0; r < 4; r++) {
        int m = wm + i * 16 + (lane >> 4) * 4 + r;
        int t = tfs[e * CAP + row0 + m];
        if (t >= 0) {
          float p = prob[t];
          size_t ro = (size_t)t * ND + n0;
          #pragma unroll
          for (int j = 0; j < 4; j++)
            outf[ro + wn + j * 16 + (lane & 15)] = (acc[i][j][r] + bn[j]) * p;
        }
      }
  }
}

extern "C" void kernel_launch(void* const* d_in, const int* in_sizes, int n_in,
                              void* d_out, int out_size, void* d_ws, size_t ws_size,
                              hipStream_t stream)
{
  const float* X  = (const float*)d_in[0];
  const float* GW = (const float*)d_in[1];
  const float* GB = (const float*)d_in[2];
  const float* W1 = (const float*)d_in[3];
  const float* B1 = (const float*)d_in[4];
  const float* W2 = (const float*)d_in[5];
  const float* B2 = (const float*)d_in[6];
  float* Y = (float*)d_out;

  char* p = (char*)d_ws;
  auto alloc = [&](size_t b) { char* r = p; p += (b + 255) & ~(size_t)255; return r; };
  ushort_t* xbf  = (ushort_t*)alloc((size_t)TT * DD * 2);        // x as bf16
  ushort_t* w1t  = (ushort_t*)alloc((size_t)EE * DD * FF * 2);   // [E][F][D] bf16
  ushort_t* w2t  = (ushort_t*)alloc((size_t)EE * FF * DD * 2);   // [E][D][F] bf16
  int*      eidx = (int*)alloc((size_t)TT * 4);
  float*    prob = (float*)alloc((size_t)TT * 4);
  int*      tpos = (int*)alloc((size_t)TT * 4);
  int*      bh   = (int*)alloc(256 * EE * 4);
  int*      bb   = (int*)alloc(256 * EE * 4);
  int*      counts = (int*)alloc(EE * 4);
  int*      tfs  = (int*)alloc((size_t)EE * CAP * 4);
  ushort_t* zrow = (ushort_t*)alloc(4096);
  size_t fixed = (size_t)(p - (char*)d_ws);
  const size_t per = (size_t)CAP * FF * 2;   // hmid bytes per expert (bf16)
  int G = 8;
  while (G > 1 && fixed + (size_t)G * per > ws_size) G >>= 1;
  ushort_t* hmid = (ushort_t*)alloc((size_t)G * per);

  hipMemsetAsync(tfs, 0xFF, (size_t)EE * CAP * 4, stream);   // all slots -> -1
  hipMemsetAsync(zrow, 0, 4096, stream);

  cast_kernel<<<TT * DD / 2048, 256, 0, stream>>>(X, xbf);
  gate_kernel<<<TT / 4, 256, 0, stream>>>(X, GW, GB, eidx, prob);
  hist_kernel<<<256, 256, 0, stream>>>(eidx, bh);
  scan_kernel<<<1, 256, 0, stream>>>(bh, bb, counts);
  rank_kernel<<<256, 256, 0, stream>>>(eidx, bb, tfs, tpos);
  zero_dropped_kernel<<<TT / 256, 256, 0, stream>>>(tpos, Y);
  transpose_cast_kernel<<<dim3(FF / 64, DD / 64, EE), 256, 0, stream>>>(W1, w1t, DD, FF);
  transpose_cast_kernel<<<dim3(DD / 64, FF / 64, EE), 256, 0, stream>>>(W2, w2t, FF, DD);

  for (int be = 0; be < EE; be += G) {
    gemm_kernel<DD, FF, false><<<dim3(8, G * 80), 256, 0, stream>>>(
        xbf, w1t, B1, tfs, counts, (const float*)nullptr, zrow, hmid, (float*)nullptr, be);
    gemm_kernel<FF, DD, true><<<dim3(2, G * 80), 256, 0, stream>>>(
        hmid, w2t, B2, tfs, counts, prob, zrow, (ushort_t*)nullptr, Y, be);
  }
}